// Round 12
// baseline (75.634 us; speedup 1.0000x reference)
//
#include <hip/hip_runtime.h>

// Problem constants (fixed by setup_inputs in the reference)
#define H        768
#define LMAX     128
#define CONV_NUM 8
#define CONV_SIZE 96
#define T_CONV   673            // H - CONV_SIZE + 1
#define FC_IN    5384           // CONV_NUM * T_CONV
#define KP       5408           // K padded to multiple of 32 (169 steps)
#define KSTEPS   (KP / 32)      // 169
#define N_WAY    10
#define K_SHOT   5
#define TOTAL_Q  150
#define SPLITK   8
#define BS       400
#define BQ       1200
#define MTOT     1600           // BS + BQ = GEMM rows (13 tiles of 128, masked)
#define NPROTO   80             // BS / K_SHOT

using s16x8 = __attribute__((ext_vector_type(8))) short;   // 8 bf16 (4 VGPRs)
using f32x4 = __attribute__((ext_vector_type(4))) float;   // MFMA acc
typedef unsigned short u16;

__device__ __forceinline__ u16 f2bf(float x) {              // RNE float->bf16 bits
    unsigned u = __float_as_uint(x);
    u += 0x7FFFu + ((u >> 16) & 1u);
    return (u16)(u >> 16);
}
__device__ __forceinline__ float bf2f(u16 b) { return __uint_as_float(((unsigned)b) << 16); }

__device__ __forceinline__ void gl16(const u16* g, u16* l) { // global->LDS 16B async
    __builtin_amdgcn_global_load_lds(
        (const __attribute__((address_space(1))) unsigned int*)g,
        (__attribute__((address_space(3))) unsigned int*)l, 16, 0, 0);
}

// ---------------------------------------------------------------------------
// 1) fused: [blocks 0..MTOT): entity-gather + MFMA conv(96) + ReLU + concat +
//    avgpool(2) -> bf16 row b of A (support rows 0..399, query 400..1599).
//    [blocks MTOT..MTOT+H): fc_W row -> bf16.
//    Gather: float4 rows (192 lanes), 4-row unroll.
// ---------------------------------------------------------------------------
#define HTS 678                 // ht bf16 stride
#define XCS 784                 // xcs stride (16B-aligned rows, <=4-way banks)
__global__ __launch_bounds__(256, 4) void pre_kernel(
    const float* __restrict__ all_support, const float* __restrict__ all_query,
    const float* __restrict__ support_emb, const float* __restrict__ query_emb,
    const float* __restrict__ fc_W,
    const int* __restrict__ s_eh, const int* __restrict__ s_eh_end,
    const int* __restrict__ s_et, const int* __restrict__ s_et_end,
    const int* __restrict__ q_eh, const int* __restrict__ q_eh_end,
    const int* __restrict__ q_et, const int* __restrict__ q_et_end,
    u16* __restrict__ A_bf, u16* __restrict__ Wh)
{
    int bid = blockIdx.x;
    int tid = threadIdx.x;

    if (bid >= MTOT) {                      // ---- W-split path (vectorized) ----
        int r = bid - MTOT;
        const float* wr = fc_W + (size_t)r * FC_IN;
        u16* whr = Wh + (size_t)r * KP;
        for (int j4 = tid; j4 < KP / 4; j4 += 256) {   // 1352 groups of 4
            int j = j4 * 4;
            ushort4 o;
            if (j4 < FC_IN / 4) {                      // 1346 full float4s
                float4 v = *(const float4*)(wr + j);
                o.x = f2bf(v.x); o.y = f2bf(v.y); o.z = f2bf(v.z); o.w = f2bf(v.w);
            } else {
                o.x = 0; o.y = 0; o.z = 0; o.w = 0;    // K-pad
            }
            *(ushort4*)(whr + j) = o;
        }
        return;
    }

    // ---- conv path ----
    __shared__ u16 htb[16 * HTS];           // 21696 B
    __shared__ u16 filt_h[16 * 96];         // combo-major: 0..7 head, 8..15 tail
    __shared__ u16 filt_l[16 * 96];
    __shared__ u16 xcs[8][XCS];             // xcs[c][j] = bf16(x[j+c]), 16B rows

    int b = bid;
    const float* src;
    int sh, eh, st, et;
    if (b < BS) {
        src = all_support + (size_t)b * LMAX * H;
        sh = s_eh[b]; eh = s_eh_end[b]; st = s_et[b]; et = s_et_end[b];
    } else {
        int m = b - BS;
        src = all_query + (size_t)m * LMAX * H;
        sh = q_eh[m]; eh = q_eh_end[m]; st = q_et[m]; et = q_et_end[m];
    }
    if (eh < sh + 1) eh = sh + 1;
    if (et < st + 1) et = st + 1;

    // entity gather -> filt hi/lo; float4 rows, 192 active lanes, 4-row unroll
    if (tid < 192) {
        const float4* base4 = (const float4*)src;      // row stride H/4 = 192
        #pragma unroll 1
        for (int ent = 0; ent < 2; ++ent) {
            int rs = ent ? st : sh, re = ent ? et : eh;
            float4 va = {0.f,0.f,0.f,0.f}, vb = va, vc = va, vd = va;
            int r = rs;
            for (; r + 4 <= re; r += 4) {
                const float4* p = base4 + (size_t)r * 192 + tid;
                float4 v0 = p[0], v1 = p[192], v2 = p[384], v3 = p[576];
                va.x += v0.x; va.y += v0.y; va.z += v0.z; va.w += v0.w;
                vb.x += v1.x; vb.y += v1.y; vb.z += v1.z; vb.w += v1.w;
                vc.x += v2.x; vc.y += v2.y; vc.z += v2.z; vc.w += v2.w;
                vd.x += v3.x; vd.y += v3.y; vd.z += v3.z; vd.w += v3.w;
            }
            for (; r < re; ++r) {
                float4 v0 = base4[(size_t)r * 192 + tid];
                va.x += v0.x; va.y += v0.y; va.z += v0.z; va.w += v0.w;
            }
            float rc = 1.0f / (float)(re - rs);
            float mm[4] = {((va.x + vb.x) + (vc.x + vd.x)) * rc,
                           ((va.y + vb.y) + (vc.y + vd.y)) * rc,
                           ((va.z + vb.z) + (vc.z + vd.z)) * rc,
                           ((va.w + vb.w) + (vc.w + vd.w)) * rc};
            int o = ent * 768 + tid * 4;
            #pragma unroll
            for (int u = 0; u < 4; ++u) {
                u16 hb = f2bf(mm[u]);
                filt_h[o + u] = hb;
                filt_l[o + u] = f2bf(mm[u] - bf2f(hb));
            }
        }
    }

    // xcs direct build: global float4 -> cvt once -> 8 shifted LDS stores.
    {
        if (tid < 192) {                     // zero tails: row=tid/24, 24 idx each
            int row = tid / 24, idx = tid % 24;
            int j = 768 - row + idx;
            if (j < XCS) xcs[row][j] = 0;
        }
        if (tid >= 192 && tid < 192 + 80) {  // htb pad: 16 rows x 5 cols
            int t = tid - 192;
            htb[(t / 5) * HTS + 673 + (t % 5)] = 0;
        }
        const float* xsrc = (b < BS) ? (support_emb + (size_t)b * H)
                                     : (query_emb + (size_t)(b - BS) * H);
        if (tid < 192) {
            float4 v = *(const float4*)(xsrc + tid * 4);
            u16 h[4] = {f2bf(v.x), f2bf(v.y), f2bf(v.z), f2bf(v.w)};
            #pragma unroll
            for (int u = 0; u < 4; ++u) {
                int i = tid * 4 + u;
                #pragma unroll
                for (int c = 0; c < 8; ++c)
                    if (i >= c) xcs[c][i - c] = h[u];
            }
        }
    }
    __syncthreads();

    // ---- MFMA conv: D[combo(16)][pos(673)] = filt(16x96) @ HankelB(96x673)
    {
        int lane = tid & 63, wv = tid >> 6;
        int n = lane & 15, g = lane >> 4;
        int afo = n * 96 + g * 8;           // A-frag: combo = n, k = g*8+j
        s16x8 fh0 = *(const s16x8*)&filt_h[afo];
        s16x8 fh1 = *(const s16x8*)&filt_h[afo + 32];
        s16x8 fh2 = *(const s16x8*)&filt_h[afo + 64];
        s16x8 fl0 = *(const s16x8*)&filt_l[afo];
        s16x8 fl1 = *(const s16x8*)&filt_l[afo + 32];
        s16x8 fl2 = *(const s16x8*)&filt_l[afo + 64];
        const u16* xrow = &xcs[n & 7][g * 8 + (n & 8)];
        #pragma unroll 1
        for (int nt = wv; nt < 43; nt += 4) {
            const u16* xp = xrow + nt * 16;
            s16x8 x0 = *(const s16x8*)(xp);
            s16x8 x1 = *(const s16x8*)(xp + 32);
            s16x8 x2 = *(const s16x8*)(xp + 64);
            f32x4 a = (f32x4){0.f, 0.f, 0.f, 0.f};
            a = __builtin_amdgcn_mfma_f32_16x16x32_bf16(fh0, x0, a, 0, 0, 0);
            a = __builtin_amdgcn_mfma_f32_16x16x32_bf16(fl0, x0, a, 0, 0, 0);
            a = __builtin_amdgcn_mfma_f32_16x16x32_bf16(fh1, x1, a, 0, 0, 0);
            a = __builtin_amdgcn_mfma_f32_16x16x32_bf16(fl1, x1, a, 0, 0, 0);
            a = __builtin_amdgcn_mfma_f32_16x16x32_bf16(fh2, x2, a, 0, 0, 0);
            a = __builtin_amdgcn_mfma_f32_16x16x32_bf16(fl2, x2, a, 0, 0, 0);
            int pcol = nt * 16 + n;         // D: col=lane&15 -> position
            if (pcol < T_CONV) {
                #pragma unroll
                for (int r = 0; r < 4; ++r) // D: row=(lane>>4)*4+r -> combo
                    htb[(g * 4 + r) * HTS + pcol] = f2bf(fmaxf(a[r], 0.f));
            }
        }
    }
    __syncthreads();

    // avgpool(2) over concat(h_f, t_f), flat-indexed; magic div by 673
    // (24929 = ceil(2^24/673), exact for i < 2^18).
    u16* oh = A_bf + (size_t)b * KP;
    for (int t = tid; t < KP / 8; t += 256) {   // 676 groups of 8
        int i0 = t * 8;
        s16x8 o;
        if (i0 < FC_IN) {
            #pragma unroll
            for (int u = 0; u < 8; ++u) {
                int i = i0 + u;                 // < 5384
                int f = (int)(((unsigned)i * 24929u) >> 24);   // i/673 exact
                int j = i - f * 673;
                int e0 = 2 * j, e1 = 2 * j + 1;
                float v0 = bf2f((e0 < T_CONV) ? htb[f * HTS + e0]
                                              : htb[(8 + f) * HTS + (e0 - T_CONV)]);
                float v1 = bf2f((e1 < T_CONV) ? htb[f * HTS + e1]
                                              : htb[(8 + f) * HTS + (e1 - T_CONV)]);
                o[u] = (short)f2bf(0.5f * (v0 + v1));
            }
        } else {
            #pragma unroll
            for (int u = 0; u < 8; ++u) o[u] = 0;   // K-pad
        }
        *(s16x8*)(oh + i0) = o;
    }
}

// ---------------------------------------------------------------------------
// 2) bf16 MFMA GEMM: C = A * W^T  (fp32 acc, bf16 C-store; bias dropped —
//    cancels in proto-query differences). M = 1600 (all rows; proto averaging
//    moved AFTER the GEMM since fc is linear).
//    128x128 tile, BK=32, 4 waves x (64x64), frag-native LDS, 2-ahead
//    counted vmcnt(4). Grid 624 = 13m x 6n x 8sk = 8 XCDs x 78 (bijective
//    chunk swizzle; each XCD owns one split-K slice ~3.2MB -> L2-resident).
//    All 624 blocks co-resident at 3 blocks/CU. Tile 12 masked (rows >= 1600).
// ---------------------------------------------------------------------------
#define ASEG 4096   // 128*32 u16 (8KB)
#define BUFU (2 * ASEG)   // 16KB per buffer

#define STAGE(ks, buf) do {                                     \
    int kb_ = (ks) * 32;                                        \
    u16* L_ = &lds[buf][0];                                     \
    gl16(Ah_g + aoff0 + kb_, L_ + cA0 * 8);                     \
    gl16(Ah_g + aoff1 + kb_, L_ + cA1 * 8);                     \
    gl16(Bh_g + boff0 + kb_, L_ + ASEG + cA0 * 8);              \
    gl16(Bh_g + boff1 + kb_, L_ + ASEG + cA1 * 8);              \
} while (0)

__global__ __launch_bounds__(256, 3) void gemm_mfma(
    const u16* __restrict__ Ah_g, const u16* __restrict__ Bh_g,
    u16* __restrict__ partsB)
{
    __shared__ u16 lds[2][BUFU];   // 32 KB

    int tid = threadIdx.x;
    // XCD-chunked bijective swizzle: 624 blocks = 8 XCDs x 78
    int wg = (blockIdx.x & 7) * 78 + (blockIdx.x >> 3);
    int sk = wg / 78;
    int rem = wg % 78;
    int n0 = (rem / 13) * 128;
    int m0 = (rem % 13) * 128;

    int ks0 = (KSTEPS * sk) / SPLITK;
    int nk = (KSTEPS * (sk + 1)) / SPLITK - ks0;   // 21 or 22

    // chunks (512 of 16B per seg): c: frag=c>>6, kg=(c>>4)&3, row=c&15
    int cA0 = tid, cA1 = tid + 256;
    int ar0 = m0 + (cA0 >> 6) * 16 + (cA0 & 15); if (ar0 >= MTOT) ar0 = MTOT - 1;
    int ar1 = m0 + (cA1 >> 6) * 16 + (cA1 & 15); if (ar1 >= MTOT) ar1 = MTOT - 1;
    size_t aoff0 = (size_t)ar0 * KP + ((cA0 >> 4) & 3) * 8;
    size_t aoff1 = (size_t)ar1 * KP + ((cA1 >> 4) & 3) * 8;
    size_t boff0 = (size_t)(n0 + (cA0 >> 6) * 16 + (cA0 & 15)) * KP + ((cA0 >> 4) & 3) * 8;
    size_t boff1 = (size_t)(n0 + (cA1 >> 6) * 16 + (cA1 & 15)) * KP + ((cA1 >> 4) & 3) * 8;

    int w = tid >> 6, lane = tid & 63;
    int wm = w >> 1, wn = w & 1;                  // 2x2 waves of 64x64
    int lfr = ((lane >> 4) * 16 + (lane & 15)) * 8;

    f32x4 acc[4][4];
    #pragma unroll
    for (int i = 0; i < 4; ++i)
        #pragma unroll
        for (int j = 0; j < 4; ++j) acc[i][j] = (f32x4){0.f, 0.f, 0.f, 0.f};

    STAGE(ks0, 0);          // 4 loads/thread in flight
    STAGE(ks0 + 1, 1);      // 8 in flight (nk >= 21 always)

    int cur = 0;
    for (int k = 0; k < nk; ++k) {
        if (k + 1 < nk) asm volatile("s_waitcnt vmcnt(4)" ::: "memory");
        else            asm volatile("s_waitcnt vmcnt(0)" ::: "memory");
        __builtin_amdgcn_s_barrier();

        const u16* L = &lds[cur][0];
        s16x8 ah[4], bh[4];
        #pragma unroll
        for (int f = 0; f < 4; ++f) {
            ah[f] = *(const s16x8*)(L + (wm * 4 + f) * 512 + lfr);
            bh[f] = *(const s16x8*)(L + ASEG + (wn * 4 + f) * 512 + lfr);
        }
        asm volatile("s_waitcnt lgkmcnt(0)" ::: "memory");
        __builtin_amdgcn_s_barrier();       // all waves done reading buf(cur)

        if (k + 2 < nk) STAGE(ks0 + k + 2, cur);   // flies under MFMA

        #pragma unroll
        for (int i = 0; i < 4; ++i)
            #pragma unroll
            for (int j = 0; j < 4; ++j)
                acc[i][j] = __builtin_amdgcn_mfma_f32_16x16x32_bf16(ah[i], bh[j], acc[i][j], 0, 0, 0);
        cur ^= 1;
    }

    // epilogue: C/D layout col=lane&15, row=(lane>>4)*4+reg  [m91-verified]
    int rbase = m0 + wm * 64 + (lane >> 4) * 4;
    int cbase = n0 + wn * 64 + (lane & 15);
    #pragma unroll
    for (int i = 0; i < 4; ++i) {
        int row0 = rbase + i * 16;
        #pragma unroll
        for (int j = 0; j < 4; ++j) {
            int col = cbase + j * 16;
            u16* dst = partsB + ((size_t)sk * MTOT + row0) * H + col;
            #pragma unroll
            for (int r = 0; r < 4; ++r)
                if (row0 + r < MTOT) dst[(size_t)r * H] = f2bf(acc[i][j][r]);
        }
    }
}

// ---------------------------------------------------------------------------
// 3) proto: proto[g] = (1/K_SHOT) sum_{k<5} sum_{sp<8} partsB[sp][g*5+k].
//    (fc linear => averaging GEMM outputs == GEMM of averaged inputs)
// ---------------------------------------------------------------------------
__global__ __launch_bounds__(192) void protofin_kernel(
    const u16* __restrict__ partsB, float* __restrict__ proto)
{
    int g = blockIdx.x;
    int d0 = threadIdx.x * 4;
    float s0 = 0.f, s1 = 0.f, s2 = 0.f, s3 = 0.f;
    #pragma unroll
    for (int sp = 0; sp < SPLITK; ++sp) {
        #pragma unroll
        for (int k = 0; k < K_SHOT; ++k) {
            size_t row = (size_t)sp * MTOT + g * K_SHOT + k;
            ushort4 v = *(const ushort4*)(partsB + row * H + d0);
            s0 += bf2f(v.x); s1 += bf2f(v.y); s2 += bf2f(v.z); s3 += bf2f(v.w);
        }
    }
    float sc = 1.0f / K_SHOT;
    *(float4*)(proto + (size_t)g * H + d0) =
        make_float4(s0 * sc, s1 * sc, s2 * sc, s3 * sc);
}

// ---------------------------------------------------------------------------
// 4) distances + logits + pred; grid = BQ blocks of 192 (3 waves, all active).
// ---------------------------------------------------------------------------
__global__ __launch_bounds__(192) void dist_kernel(
    const u16* __restrict__ partsB, const float* __restrict__ proto,
    float* __restrict__ outp)
{
    int bid = blockIdx.x;            // e*TOTAL_Q + q
    int e = bid / TOTAL_Q;
    int tid = threadIdx.x;
    int m = BS + bid;                // GEMM row of this query
    int d0 = tid * 4;                // 192 threads cover 768 dims

    float qv0 = 0.f, qv1 = 0.f, qv2 = 0.f, qv3 = 0.f;
    #pragma unroll
    for (int sp = 0; sp < SPLITK; ++sp) {
        ushort4 v = *(const ushort4*)(partsB + ((size_t)sp * MTOT + m) * H + d0);
        qv0 += bf2f(v.x); qv1 += bf2f(v.y); qv2 += bf2f(v.z); qv3 += bf2f(v.w);
    }

    __shared__ float red[N_WAY][3];
    __shared__ float lvals[N_WAY];
    int wave = tid >> 6, lane = tid & 63;
    for (int n = 0; n < N_WAY; ++n) {
        const float* pr = proto + (size_t)(e * N_WAY + n) * H + d0;
        float4 pv = *(const float4*)pr;
        float df0 = pv.x - qv0, df1 = pv.y - qv1, df2 = pv.z - qv2, df3 = pv.w - qv3;
        float p = df0 * df0;
        p = fmaf(df1, df1, p);
        p = fmaf(df2, df2, p);
        p = fmaf(df3, df3, p);
        #pragma unroll
        for (int off = 32; off > 0; off >>= 1)
            p += __shfl_down(p, off);
        if (lane == 0) red[n][wave] = p;
    }
    __syncthreads();
    if (tid < N_WAY) {
        float v = red[tid][0] + red[tid][1] + red[tid][2];
        lvals[tid] = -v;
        outp[(size_t)bid * (N_WAY + 1) + tid] = -v;
    }
    __syncthreads();
    if (tid == 0) {
        float mn = lvals[0];
        #pragma unroll
        for (int n = 1; n < N_WAY; ++n) mn = fminf(mn, lvals[n]);
        float last = mn - 1.0f;
        outp[(size_t)bid * (N_WAY + 1) + N_WAY] = last;
        float best = lvals[0];
        int bi = 0;
        for (int n = 1; n < N_WAY; ++n)
            if (lvals[n] > best) { best = lvals[n]; bi = n; }
        if (last > best) bi = N_WAY;   // parity with reference; cannot trigger
        outp[(size_t)BQ * (N_WAY + 1) + bid] = (float)bi;
    }
}

// ---------------------------------------------------------------------------
extern "C" void kernel_launch(void* const* d_in, const int* in_sizes, int n_in,
                              void* d_out, int out_size, void* d_ws, size_t ws_size,
                              hipStream_t stream)
{
    const float* all_support = (const float*)d_in[0];
    const float* support_emb = (const float*)d_in[1];
    const float* all_query   = (const float*)d_in[2];
    const float* query_emb   = (const float*)d_in[3];
    const float* fc_W        = (const float*)d_in[4];
    const int* s_eh     = (const int*)d_in[6];
    const int* s_eh_end = (const int*)d_in[7];
    const int* s_et     = (const int*)d_in[8];
    const int* s_et_end = (const int*)d_in[9];
    const int* q_eh     = (const int*)d_in[10];
    const int* q_eh_end = (const int*)d_in[11];
    const int* q_et     = (const int*)d_in[12];
    const int* q_et_end = (const int*)d_in[13];

    // workspace layout (all segment sizes multiples of 16B)
    u16* partsB  = (u16*)d_ws;                                  // SPLITK*MTOT*H u16
    float* proto = (float*)(partsB + (size_t)SPLITK * MTOT * H);// NPROTO*H f32
    u16* Wh      = (u16*)(proto + (size_t)NPROTO * H);          // H*KP
    u16* A_bf    = Wh + (size_t)H * KP;                         // MTOT*KP

    pre_kernel<<<MTOT + H, 256, 0, stream>>>(
        all_support, all_query, support_emb, query_emb, fc_W,
        s_eh, s_eh_end, s_et, s_et_end, q_eh, q_eh_end, q_et, q_et_end,
        A_bf, Wh);

    gemm_mfma<<<624, 256, 0, stream>>>(A_bf, Wh, partsB);

    protofin_kernel<<<NPROTO, 192, 0, stream>>>(partsB, proto);

    dist_kernel<<<BQ, 192, 0, stream>>>(partsB, proto, (float*)d_out);
}

// Round 13
// 68.286 us; speedup vs baseline: 1.1076x; 1.1076x over previous
//
#include <hip/hip_runtime.h>

// Problem constants (fixed by setup_inputs in the reference)
#define H        768
#define LMAX     128
#define CONV_NUM 8
#define CONV_SIZE 96
#define T_CONV   673            // H - CONV_SIZE + 1
#define FC_IN    5384           // CONV_NUM * T_CONV
#define KP       5408           // K padded to multiple of 32 (169 steps)
#define KSTEPS   (KP / 32)      // 169
#define N_WAY    10
#define K_SHOT   5
#define TOTAL_Q  150
#define SPLITK   4
#define BS       400
#define BQ       1200
#define MTOT     1600           // BS + BQ
#define NPROTO   80             // BS / K_SHOT
#define MA       1280           // NPROTO + BQ  (GEMM rows; 10 tiles of 128)

using s16x8 = __attribute__((ext_vector_type(8))) short;   // 8 bf16 (4 VGPRs)
using f32x4 = __attribute__((ext_vector_type(4))) float;   // MFMA acc
typedef unsigned short u16;

__device__ __forceinline__ u16 f2bf(float x) {              // RNE float->bf16 bits
    unsigned u = __float_as_uint(x);
    u += 0x7FFFu + ((u >> 16) & 1u);
    return (u16)(u >> 16);
}
__device__ __forceinline__ float bf2f(u16 b) { return __uint_as_float(((unsigned)b) << 16); }

__device__ __forceinline__ void gl16(const u16* g, u16* l) { // global->LDS 16B async
    __builtin_amdgcn_global_load_lds(
        (const __attribute__((address_space(1))) unsigned int*)g,
        (__attribute__((address_space(3))) unsigned int*)l, 16, 0, 0);
}

// ---------------------------------------------------------------------------
// 1) fused: [blocks 0..MTOT): entity-gather + MFMA conv(96) + ReLU + concat +
//    avgpool(2) -> bf16 rows.  Support rows -> flatS, query rows -> A[80..).
//    [blocks MTOT..MTOT+H): fc_W row -> bf16 (float4/ushort4 vectorized).
//    (identical to round 11 — best validated)
// ---------------------------------------------------------------------------
#define HTS 678                 // ht bf16 stride
#define XCS 784                 // xcs stride (16B-aligned rows, <=4-way banks)
__global__ __launch_bounds__(256, 4) void pre_kernel(
    const float* __restrict__ all_support, const float* __restrict__ all_query,
    const float* __restrict__ support_emb, const float* __restrict__ query_emb,
    const float* __restrict__ fc_W,
    const int* __restrict__ s_eh, const int* __restrict__ s_eh_end,
    const int* __restrict__ s_et, const int* __restrict__ s_et_end,
    const int* __restrict__ q_eh, const int* __restrict__ q_eh_end,
    const int* __restrict__ q_et, const int* __restrict__ q_et_end,
    u16* __restrict__ flatS, u16* __restrict__ A_bf,
    u16* __restrict__ Wh)
{
    int bid = blockIdx.x;
    int tid = threadIdx.x;

    if (bid >= MTOT) {                      // ---- W-split path (vectorized) ----
        int r = bid - MTOT;
        const float* wr = fc_W + (size_t)r * FC_IN;
        u16* whr = Wh + (size_t)r * KP;
        for (int j4 = tid; j4 < KP / 4; j4 += 256) {   // 1352 groups of 4
            int j = j4 * 4;
            ushort4 o;
            if (j4 < FC_IN / 4) {                      // 1346 full float4s
                float4 v = *(const float4*)(wr + j);
                o.x = f2bf(v.x); o.y = f2bf(v.y); o.z = f2bf(v.z); o.w = f2bf(v.w);
            } else {
                o.x = 0; o.y = 0; o.z = 0; o.w = 0;    // K-pad
            }
            *(ushort4*)(whr + j) = o;
        }
        return;
    }

    // ---- conv path ----
    __shared__ u16 htb[16 * HTS];           // 21696 B
    __shared__ u16 filt_h[16 * 96];         // combo-major: 0..7 head, 8..15 tail
    __shared__ u16 filt_l[16 * 96];
    __shared__ u16 xcs[8][XCS];             // xcs[c][j] = bf16(x[j+c]), 16B rows

    int b = bid;
    const float* src;
    int sh, eh, st, et;
    if (b < BS) {
        src = all_support + (size_t)b * LMAX * H;
        sh = s_eh[b]; eh = s_eh_end[b]; st = s_et[b]; et = s_et_end[b];
    } else {
        int m = b - BS;
        src = all_query + (size_t)m * LMAX * H;
        sh = q_eh[m]; eh = q_eh_end[m]; st = q_et[m]; et = q_et_end[m];
    }
    if (eh < sh + 1) eh = sh + 1;
    if (et < st + 1) et = st + 1;

    {   // entity gather -> filt hi/lo; 4x-unrolled, 12 independent load chains
        float a0 = 0.f, a1 = 0.f, a2 = 0.f, b0 = 0.f, b1 = 0.f, b2 = 0.f;
        float c0 = 0.f, c1 = 0.f, c2 = 0.f, d0 = 0.f, d1 = 0.f, d2 = 0.f;
        int r = sh;
        for (; r + 4 <= eh; r += 4) {
            const float* p0 = src + (size_t)r * H;
            const float* p1 = p0 + H;
            const float* p2 = p0 + 2 * H;
            const float* p3 = p0 + 3 * H;
            a0 += p0[tid]; a1 += p0[tid + 256]; a2 += p0[tid + 512];
            b0 += p1[tid]; b1 += p1[tid + 256]; b2 += p1[tid + 512];
            c0 += p2[tid]; c1 += p2[tid + 256]; c2 += p2[tid + 512];
            d0 += p3[tid]; d1 += p3[tid + 256]; d2 += p3[tid + 512];
        }
        for (; r < eh; ++r) {
            const float* p0 = src + (size_t)r * H;
            a0 += p0[tid]; a1 += p0[tid + 256]; a2 += p0[tid + 512];
        }
        float rc = 1.0f / (float)(eh - sh);
        float m0 = ((a0 + b0) + (c0 + d0)) * rc;
        float m1 = ((a1 + b1) + (c1 + d1)) * rc;
        float m2 = ((a2 + b2) + (c2 + d2)) * rc;
        u16 h0 = f2bf(m0), h1 = f2bf(m1), h2 = f2bf(m2);
        filt_h[tid] = h0;       filt_l[tid] = f2bf(m0 - bf2f(h0));
        filt_h[tid + 256] = h1; filt_l[tid + 256] = f2bf(m1 - bf2f(h1));
        filt_h[tid + 512] = h2; filt_l[tid + 512] = f2bf(m2 - bf2f(h2));
        a0 = a1 = a2 = b0 = b1 = b2 = c0 = c1 = c2 = d0 = d1 = d2 = 0.f;
        r = st;
        for (; r + 4 <= et; r += 4) {
            const float* p0 = src + (size_t)r * H;
            const float* p1 = p0 + H;
            const float* p2 = p0 + 2 * H;
            const float* p3 = p0 + 3 * H;
            a0 += p0[tid]; a1 += p0[tid + 256]; a2 += p0[tid + 512];
            b0 += p1[tid]; b1 += p1[tid + 256]; b2 += p1[tid + 512];
            c0 += p2[tid]; c1 += p2[tid + 256]; c2 += p2[tid + 512];
            d0 += p3[tid]; d1 += p3[tid + 256]; d2 += p3[tid + 512];
        }
        for (; r < et; ++r) {
            const float* p0 = src + (size_t)r * H;
            a0 += p0[tid]; a1 += p0[tid + 256]; a2 += p0[tid + 512];
        }
        rc = 1.0f / (float)(et - st);
        m0 = ((a0 + b0) + (c0 + d0)) * rc;
        m1 = ((a1 + b1) + (c1 + d1)) * rc;
        m2 = ((a2 + b2) + (c2 + d2)) * rc;
        h0 = f2bf(m0); h1 = f2bf(m1); h2 = f2bf(m2);
        filt_h[tid + 768] = h0;  filt_l[tid + 768] = f2bf(m0 - bf2f(h0));
        filt_h[tid + 1024] = h1; filt_l[tid + 1024] = f2bf(m1 - bf2f(h1));
        filt_h[tid + 1280] = h2; filt_l[tid + 1280] = f2bf(m2 - bf2f(h2));
    }

    // xcs direct build: global float4 -> cvt once -> 8 shifted LDS stores.
    {
        if (tid < 192) {                     // zero tails: row=tid/24, 24 idx each
            int row = tid / 24, idx = tid % 24;
            int j = 768 - row + idx;
            if (j < XCS) xcs[row][j] = 0;
        }
        if (tid >= 192 && tid < 192 + 80) {  // htb pad: 16 rows x 5 cols
            int t = tid - 192;
            htb[(t / 5) * HTS + 673 + (t % 5)] = 0;
        }
        const float* xsrc = (b < BS) ? (support_emb + (size_t)b * H)
                                     : (query_emb + (size_t)(b - BS) * H);
        if (tid < 192) {
            float4 v = *(const float4*)(xsrc + tid * 4);
            u16 h[4] = {f2bf(v.x), f2bf(v.y), f2bf(v.z), f2bf(v.w)};
            #pragma unroll
            for (int u = 0; u < 4; ++u) {
                int i = tid * 4 + u;
                #pragma unroll
                for (int c = 0; c < 8; ++c)
                    if (i >= c) xcs[c][i - c] = h[u];
            }
        }
    }
    __syncthreads();

    // ---- MFMA conv: D[combo(16)][pos(673)] = filt(16x96) @ HankelB(96x673)
    {
        int lane = tid & 63, wv = tid >> 6;
        int n = lane & 15, g = lane >> 4;
        int afo = n * 96 + g * 8;           // A-frag: combo = n, k = g*8+j
        s16x8 fh0 = *(const s16x8*)&filt_h[afo];
        s16x8 fh1 = *(const s16x8*)&filt_h[afo + 32];
        s16x8 fh2 = *(const s16x8*)&filt_h[afo + 64];
        s16x8 fl0 = *(const s16x8*)&filt_l[afo];
        s16x8 fl1 = *(const s16x8*)&filt_l[afo + 32];
        s16x8 fl2 = *(const s16x8*)&filt_l[afo + 64];
        const u16* xrow = &xcs[n & 7][g * 8 + (n & 8)];
        #pragma unroll 1
        for (int nt = wv; nt < 43; nt += 4) {
            const u16* xp = xrow + nt * 16;
            s16x8 x0 = *(const s16x8*)(xp);
            s16x8 x1 = *(const s16x8*)(xp + 32);
            s16x8 x2 = *(const s16x8*)(xp + 64);
            f32x4 a = (f32x4){0.f, 0.f, 0.f, 0.f};
            a = __builtin_amdgcn_mfma_f32_16x16x32_bf16(fh0, x0, a, 0, 0, 0);
            a = __builtin_amdgcn_mfma_f32_16x16x32_bf16(fl0, x0, a, 0, 0, 0);
            a = __builtin_amdgcn_mfma_f32_16x16x32_bf16(fh1, x1, a, 0, 0, 0);
            a = __builtin_amdgcn_mfma_f32_16x16x32_bf16(fl1, x1, a, 0, 0, 0);
            a = __builtin_amdgcn_mfma_f32_16x16x32_bf16(fh2, x2, a, 0, 0, 0);
            a = __builtin_amdgcn_mfma_f32_16x16x32_bf16(fl2, x2, a, 0, 0, 0);
            int pcol = nt * 16 + n;         // D: col=lane&15 -> position
            if (pcol < T_CONV) {
                #pragma unroll
                for (int r = 0; r < 4; ++r) // D: row=(lane>>4)*4+r -> combo
                    htb[(g * 4 + r) * HTS + pcol] = f2bf(fmaxf(a[r], 0.f));
            }
        }
    }
    __syncthreads();

    // avgpool(2) over concat(h_f, t_f), flat-indexed; magic div by 673
    // (24929 = ceil(2^24/673), exact for i < 2^18).
    u16* oh = (b < BS) ? (flatS + (size_t)b * KP)
                       : (A_bf + (size_t)(NPROTO + b - BS) * KP);
    for (int t = tid; t < KP / 8; t += 256) {   // 676 groups of 8
        int i0 = t * 8;
        s16x8 o;
        if (i0 < FC_IN) {
            #pragma unroll
            for (int u = 0; u < 8; ++u) {
                int i = i0 + u;                 // < 5384
                int f = (int)(((unsigned)i * 24929u) >> 24);   // i/673 exact
                int j = i - f * 673;
                int e0 = 2 * j, e1 = 2 * j + 1;
                float v0 = bf2f((e0 < T_CONV) ? htb[f * HTS + e0]
                                              : htb[(8 + f) * HTS + (e0 - T_CONV)]);
                float v1 = bf2f((e1 < T_CONV) ? htb[f * HTS + e1]
                                              : htb[(8 + f) * HTS + (e1 - T_CONV)]);
                o[u] = (short)f2bf(0.5f * (v0 + v1));
            }
        } else {
            #pragma unroll
            for (int u = 0; u < 8; ++u) o[u] = 0;   // K-pad
        }
        *(s16x8*)(oh + i0) = o;
    }
}

// ---------------------------------------------------------------------------
// 2) support pre-average (fc linear => mean-before == mean-after), 16B vec.
//    grid (80, 3): t = by*256+tid covers all 676 groups of 8.
// ---------------------------------------------------------------------------
__global__ __launch_bounds__(256) void avg_kernel(
    const u16* __restrict__ flatS, u16* __restrict__ A_bf)
{
    int i = blockIdx.x;                   // proto row 0..79
    int t = blockIdx.y * 256 + threadIdx.x;
    if (t >= KP / 8) return;
    size_t base = (size_t)i * K_SHOT * KP;
    int j = t * 8;
    float s[8] = {0.f, 0.f, 0.f, 0.f, 0.f, 0.f, 0.f, 0.f};
    #pragma unroll
    for (int k = 0; k < K_SHOT; ++k) {
        s16x8 vh = *(const s16x8*)(flatS + base + (size_t)k * KP + j);
        #pragma unroll
        for (int u = 0; u < 8; ++u)
            s[u] += bf2f((u16)vh[u]);
    }
    s16x8 oh;
    #pragma unroll
    for (int u = 0; u < 8; ++u)
        oh[u] = (short)f2bf(s[u] * (1.0f / K_SHOT));
    *(s16x8*)(A_bf + (size_t)i * KP + j) = oh;
}

// ---------------------------------------------------------------------------
// 3) bf16 MFMA GEMM: C = A * W^T  (fp32 acc, bf16 C-store; bias dropped).
//    128x128 tile, BK=32, 4 waves x (64x64), frag-native LDS, 2-ahead
//    counted vmcnt(4). SPLITK=4: grid 240 = 10m x 6n x 4sk = 8 XCDs x 30
//    (bijective chunk swizzle). Halves partsB write+read traffic vs SPLITK=8;
//    42-43 K-steps/block amortize the pipeline better.
// ---------------------------------------------------------------------------
#define ASEG 4096   // 128*32 u16 (8KB)
#define BUFU (2 * ASEG)   // 16KB per buffer

#define STAGE(ks, buf) do {                                     \
    int kb_ = (ks) * 32;                                        \
    u16* L_ = &lds[buf][0];                                     \
    gl16(Ah_g + aoff0 + kb_, L_ + cA0 * 8);                     \
    gl16(Ah_g + aoff1 + kb_, L_ + cA1 * 8);                     \
    gl16(Bh_g + boff0 + kb_, L_ + ASEG + cA0 * 8);              \
    gl16(Bh_g + boff1 + kb_, L_ + ASEG + cA1 * 8);              \
} while (0)

__global__ __launch_bounds__(256, 3) void gemm_mfma(
    const u16* __restrict__ Ah_g, const u16* __restrict__ Bh_g,
    u16* __restrict__ partsB)
{
    __shared__ u16 lds[2][BUFU];   // 32 KB

    int tid = threadIdx.x;
    // XCD-chunked bijective swizzle: 240 blocks = 8 XCDs x 30
    int wg = (blockIdx.x & 7) * 30 + (blockIdx.x >> 3);
    int sk = wg / 60;
    int rem = wg % 60;
    int n0 = (rem / 10) * 128;
    int m0 = (rem % 10) * 128;

    int ks0 = (KSTEPS * sk) / SPLITK;
    int nk = (KSTEPS * (sk + 1)) / SPLITK - ks0;   // 42 or 43

    // chunks (512 of 16B per seg): c: frag=c>>6, kg=(c>>4)&3, row=c&15
    int cA0 = tid, cA1 = tid + 256;
    size_t aoff0 = (size_t)(m0 + (cA0 >> 6) * 16 + (cA0 & 15)) * KP + ((cA0 >> 4) & 3) * 8;
    size_t aoff1 = (size_t)(m0 + (cA1 >> 6) * 16 + (cA1 & 15)) * KP + ((cA1 >> 4) & 3) * 8;
    size_t boff0 = (size_t)(n0 + (cA0 >> 6) * 16 + (cA0 & 15)) * KP + ((cA0 >> 4) & 3) * 8;
    size_t boff1 = (size_t)(n0 + (cA1 >> 6) * 16 + (cA1 & 15)) * KP + ((cA1 >> 4) & 3) * 8;

    int w = tid >> 6, lane = tid & 63;
    int wm = w >> 1, wn = w & 1;                  // 2x2 waves of 64x64
    int lfr = ((lane >> 4) * 16 + (lane & 15)) * 8;

    f32x4 acc[4][4];
    #pragma unroll
    for (int i = 0; i < 4; ++i)
        #pragma unroll
        for (int j = 0; j < 4; ++j) acc[i][j] = (f32x4){0.f, 0.f, 0.f, 0.f};

    STAGE(ks0, 0);          // 4 loads/thread in flight
    STAGE(ks0 + 1, 1);      // 8 in flight (nk >= 42 always)

    int cur = 0;
    for (int k = 0; k < nk; ++k) {
        if (k + 1 < nk) asm volatile("s_waitcnt vmcnt(4)" ::: "memory");
        else            asm volatile("s_waitcnt vmcnt(0)" ::: "memory");
        __builtin_amdgcn_s_barrier();

        const u16* L = &lds[cur][0];
        s16x8 ah[4], bh[4];
        #pragma unroll
        for (int f = 0; f < 4; ++f) {
            ah[f] = *(const s16x8*)(L + (wm * 4 + f) * 512 + lfr);
            bh[f] = *(const s16x8*)(L + ASEG + (wn * 4 + f) * 512 + lfr);
        }
        asm volatile("s_waitcnt lgkmcnt(0)" ::: "memory");
        __builtin_amdgcn_s_barrier();       // all waves done reading buf(cur)

        if (k + 2 < nk) STAGE(ks0 + k + 2, cur);   // flies under MFMA

        #pragma unroll
        for (int i = 0; i < 4; ++i)
            #pragma unroll
            for (int j = 0; j < 4; ++j)
                acc[i][j] = __builtin_amdgcn_mfma_f32_16x16x32_bf16(ah[i], bh[j], acc[i][j], 0, 0, 0);
        cur ^= 1;
    }

    // epilogue: C/D layout col=lane&15, row=(lane>>4)*4+reg  [m91-verified]
    int rbase = m0 + wm * 64 + (lane >> 4) * 4;
    int cbase = n0 + wn * 64 + (lane & 15);
    #pragma unroll
    for (int i = 0; i < 4; ++i) {
        int row0 = rbase + i * 16;
        #pragma unroll
        for (int j = 0; j < 4; ++j) {
            int col = cbase + j * 16;
            u16* dst = partsB + ((size_t)sk * MA + row0) * H + col;
            #pragma unroll
            for (int r = 0; r < 4; ++r)
                dst[(size_t)r * H] = f2bf(acc[i][j][r]);
        }
    }
}

// ---------------------------------------------------------------------------
// 4) proto finalize: proto[i] = sum_split partsB[sp][i]  (i < 80), ushort4.
// ---------------------------------------------------------------------------
__global__ __launch_bounds__(192) void protofin_kernel(
    const u16* __restrict__ partsB, float* __restrict__ proto)
{
    int i = blockIdx.x;
    int d0 = threadIdx.x * 4;
    float s0 = 0.f, s1 = 0.f, s2 = 0.f, s3 = 0.f;
    #pragma unroll
    for (int sp = 0; sp < SPLITK; ++sp) {
        ushort4 v = *(const ushort4*)(partsB + ((size_t)sp * MA + i) * H + d0);
        s0 += bf2f(v.x); s1 += bf2f(v.y); s2 += bf2f(v.z); s3 += bf2f(v.w);
    }
    *(float4*)(proto + (size_t)i * H + d0) = make_float4(s0, s1, s2, s3);
}

// ---------------------------------------------------------------------------
// 5) distances + logits + pred; grid = BQ blocks of 192 (3 waves, all active).
// ---------------------------------------------------------------------------
__global__ __launch_bounds__(192) void dist_kernel(
    const u16* __restrict__ partsB, const float* __restrict__ proto,
    float* __restrict__ outp)
{
    int bid = blockIdx.x;            // e*TOTAL_Q + q
    int e = bid / TOTAL_Q;
    int tid = threadIdx.x;
    int m = NPROTO + bid;            // GEMM row of this query
    int d0 = tid * 4;                // 192 threads cover 768 dims

    float qv0 = 0.f, qv1 = 0.f, qv2 = 0.f, qv3 = 0.f;
    #pragma unroll
    for (int sp = 0; sp < SPLITK; ++sp) {
        ushort4 v = *(const ushort4*)(partsB + ((size_t)sp * MA + m) * H + d0);
        qv0 += bf2f(v.x); qv1 += bf2f(v.y); qv2 += bf2f(v.z); qv3 += bf2f(v.w);
    }

    __shared__ float red[N_WAY][3];
    __shared__ float lvals[N_WAY];
    int wave = tid >> 6, lane = tid & 63;
    for (int n = 0; n < N_WAY; ++n) {
        const float* pr = proto + (size_t)(e * N_WAY + n) * H + d0;
        float4 pv = *(const float4*)pr;
        float df0 = pv.x - qv0, df1 = pv.y - qv1, df2 = pv.z - qv2, df3 = pv.w - qv3;
        float p = df0 * df0;
        p = fmaf(df1, df1, p);
        p = fmaf(df2, df2, p);
        p = fmaf(df3, df3, p);
        #pragma unroll
        for (int off = 32; off > 0; off >>= 1)
            p += __shfl_down(p, off);
        if (lane == 0) red[n][wave] = p;
    }
    __syncthreads();
    if (tid < N_WAY) {
        float v = red[tid][0] + red[tid][1] + red[tid][2];
        lvals[tid] = -v;
        outp[(size_t)bid * (N_WAY + 1) + tid] = -v;
    }
    __syncthreads();
    if (tid == 0) {
        float mn = lvals[0];
        #pragma unroll
        for (int n = 1; n < N_WAY; ++n) mn = fminf(mn, lvals[n]);
        float last = mn - 1.0f;
        outp[(size_t)bid * (N_WAY + 1) + N_WAY] = last;
        float best = lvals[0];
        int bi = 0;
        for (int n = 1; n < N_WAY; ++n)
            if (lvals[n] > best) { best = lvals[n]; bi = n; }
        if (last > best) bi = N_WAY;   // parity with reference; cannot trigger
        outp[(size_t)BQ * (N_WAY + 1) + bid] = (float)bi;
    }
}

// ---------------------------------------------------------------------------
extern "C" void kernel_launch(void* const* d_in, const int* in_sizes, int n_in,
                              void* d_out, int out_size, void* d_ws, size_t ws_size,
                              hipStream_t stream)
{
    const float* all_support = (const float*)d_in[0];
    const float* support_emb = (const float*)d_in[1];
    const float* all_query   = (const float*)d_in[2];
    const float* query_emb   = (const float*)d_in[3];
    const float* fc_W        = (const float*)d_in[4];
    const int* s_eh     = (const int*)d_in[6];
    const int* s_eh_end = (const int*)d_in[7];
    const int* s_et     = (const int*)d_in[8];
    const int* s_et_end = (const int*)d_in[9];
    const int* q_eh     = (const int*)d_in[10];
    const int* q_eh_end = (const int*)d_in[11];
    const int* q_et     = (const int*)d_in[12];
    const int* q_et_end = (const int*)d_in[13];

    // workspace layout (all segment sizes multiples of 16B)
    u16* partsB  = (u16*)d_ws;                             // SPLITK*MA*H u16
    float* proto = (float*)(partsB + (size_t)SPLITK * MA * H);  // NPROTO*H f32
    u16* Wh      = (u16*)(proto + (size_t)NPROTO * H);     // H*KP
    u16* A_bf    = Wh + (size_t)H * KP;                    // MA*KP
    u16* flatS   = A_bf + (size_t)MA * KP;                 // BS*KP

    pre_kernel<<<MTOT + H, 256, 0, stream>>>(
        all_support, all_query, support_emb, query_emb, fc_W,
        s_eh, s_eh_end, s_et, s_et_end, q_eh, q_eh_end, q_et, q_et_end,
        flatS, A_bf, Wh);

    avg_kernel<<<dim3(NPROTO, 3), 256, 0, stream>>>(flatS, A_bf);

    gemm_mfma<<<240, 256, 0, stream>>>(A_bf, Wh, partsB);

    protofin_kernel<<<NPROTO, 192, 0, stream>>>(partsB, proto);

    dist_kernel<<<BQ, 192, 0, stream>>>(partsB, proto, (float*)d_out);
}